// Round 4
// baseline (1344.407 us; speedup 1.0000x reference)
//
#include <hip/hip_runtime.h>
#include <hip/hip_bf16.h>
#include <math.h>

// Problem constants (fixed by the reference)
#define B_ROWS 16384
#define D_DIM  4096
#define H_DIM  2048
#define E_DIM  64
#define TEMP   0.8f

typedef __bf16 bf16x8 __attribute__((ext_vector_type(8)));
typedef float  f32x4  __attribute__((ext_vector_type(4)));
typedef float  f32x16 __attribute__((ext_vector_type(16)));
typedef unsigned short ushort8 __attribute__((ext_vector_type(8)));

__device__ __forceinline__ unsigned short bf_rne(float f) {
  unsigned u = __float_as_uint(f);
  u += 0x7FFF + ((u >> 16) & 1);
  return (unsigned short)(u >> 16);
}

__device__ __forceinline__ void async_copy16(const void* g, void* l) {
  __builtin_amdgcn_global_load_lds(
      (const __attribute__((address_space(1))) void*)g,
      (__attribute__((address_space(3))) void*)l, 16, 0, 0);
}

// ---------------------------------------------------------------------------
// split: fp32 -> (hi bf16, lo bf16), RNE both. 8 elements / thread.
// Optionally zeros *zp from block 0 thread 0 (folds the accum-zero launch).
// ---------------------------------------------------------------------------
__global__ __launch_bounds__(256) void split_kernel(
    const float* __restrict__ in, unsigned short* __restrict__ hi,
    unsigned short* __restrict__ lo, float* zp) {
  if (zp && blockIdx.x == 0 && threadIdx.x == 0) *zp = 0.f;
  const size_t i = ((size_t)blockIdx.x * 256 + threadIdx.x) * 8;
  float4 v0 = *(const float4*)(in + i);
  float4 v1 = *(const float4*)(in + i + 4);
  float f[8] = {v0.x, v0.y, v0.z, v0.w, v1.x, v1.y, v1.z, v1.w};
  ushort8 hv, lv;
#pragma unroll
  for (int j = 0; j < 8; ++j) {
    unsigned short h = bf_rne(f[j]);
    float fh = __uint_as_float(((unsigned)h) << 16);
    hv[j] = h;
    lv[j] = bf_rne(f[j] - fh);
  }
  *(ushort8*)(hi + i) = hv;
  *(ushort8*)(lo + i) = lv;
}

// ---------------------------------------------------------------------------
// K1: h = relu(x @ W1^T + b1) via bf16x3 MFMA emulation of fp32.
// R4: switched 16x16x32 -> 32x32x16 frags (higher MFMA ceiling, half the
// MFMA instruction count). Wave tile 64x64 = 2x2 frags of 32x32.
// A-frag: lane holds A[m=lane&31][k=(lane>>5)*8+j]; B mirrors with n.
// C/D: col=lane&31, row=(reg&3)+8*(reg>>2)+4*(lane>>5)  [m74/m101 verified]
// ---------------------------------------------------------------------------
#define BM 128
#define BN 128
#define BKK 32

__global__ __launch_bounds__(256) void gemm1_mfma_kernel(
    const float* __restrict__ x,
    const unsigned short* __restrict__ w1h,
    const unsigned short* __restrict__ w1l,
    const float* __restrict__ b1, float* __restrict__ Hout) {
  __shared__ unsigned short Ah[BM * BKK];  // 8 KB each
  __shared__ unsigned short Al[BM * BKK];
  __shared__ unsigned short Bh[BN * BKK];
  __shared__ unsigned short Bl[BN * BKK];

  const int t    = threadIdx.x;
  const int lane = t & 63;
  const int w    = t >> 6;          // wave 0..3
  const int wm   = w >> 1;          // wave m (2)
  const int wn   = w & 1;           // wave n (2)
  const int m0   = blockIdx.y * BM;
  const int n0   = blockIdx.x * BN;

  // --- B staging via global_load_lds (wave-uniform base + lane*16B) ---
  const int e0 = (w * 2 + 0) * 512 + lane * 8;
  const int e1 = (w * 2 + 1) * 512 + lane * 8;
  const int r0 = e0 >> 5, c0 = e0 & 31;
  const int r1 = e1 >> 5, c1 = e1 & 31;
  const unsigned short* bh_g0 = w1h + (size_t)(n0 + r0) * D_DIM + c0;
  const unsigned short* bh_g1 = w1h + (size_t)(n0 + r1) * D_DIM + c1;
  const unsigned short* bl_g0 = w1l + (size_t)(n0 + r0) * D_DIM + c0;
  const unsigned short* bl_g1 = w1l + (size_t)(n0 + r1) * D_DIM + c1;
  unsigned short* bh_l0 = &Bh[e0];
  unsigned short* bh_l1 = &Bh[e1];
  unsigned short* bl_l0 = &Bl[e0];
  unsigned short* bl_l1 = &Bl[e1];

  // --- A staging (fp32 -> hi/lo bf16 in-kernel) ---
  const int ar = t >> 1;
  const int ac = (t & 1) * 16;
  const float* xp = x + (size_t)(m0 + ar) * D_DIM + ac;
  unsigned short* ah_w = &Ah[ar * BKK + ac];
  unsigned short* al_w = &Al[ar * BKK + ac];

  // --- fragment LDS read addresses (32x32 layout) ---
  const int koff = (lane >> 5) * 8;                 // 0 or 8
  const unsigned short* a_rd[2];
  const unsigned short* b_rd[2];
#pragma unroll
  for (int f = 0; f < 2; ++f) {
    a_rd[f] = &Ah[(wm * 64 + f * 32 + (lane & 31)) * BKK + koff];
    b_rd[f] = &Bh[(wn * 64 + f * 32 + (lane & 31)) * BKK + koff];
  }
  const int lo_off_a = (int)(Al - Ah);
  const int lo_off_b = (int)(Bl - Bh);

  f32x16 acc[2][2];
#pragma unroll
  for (int i = 0; i < 2; ++i)
#pragma unroll
    for (int j = 0; j < 2; ++j) acc[i][j] = (f32x16)0.f;

  for (int k0 = 0; k0 < D_DIM; k0 += BKK) {
    async_copy16(bh_g0 + k0, bh_l0);
    async_copy16(bh_g1 + k0, bh_l1);
    async_copy16(bl_g0 + k0, bl_l0);
    async_copy16(bl_g1 + k0, bl_l1);

    float4 v[4];
#pragma unroll
    for (int j = 0; j < 4; ++j) v[j] = *(const float4*)(xp + k0 + j * 4);
    float f[16] = {v[0].x, v[0].y, v[0].z, v[0].w, v[1].x, v[1].y, v[1].z, v[1].w,
                   v[2].x, v[2].y, v[2].z, v[2].w, v[3].x, v[3].y, v[3].z, v[3].w};
    ushort8 hv0, hv1, lv0, lv1;
#pragma unroll
    for (int j = 0; j < 8; ++j) {
      unsigned short h = bf_rne(f[j]);
      float fh = __uint_as_float(((unsigned)h) << 16);
      hv0[j] = h;
      lv0[j] = bf_rne(f[j] - fh);
    }
#pragma unroll
    for (int j = 0; j < 8; ++j) {
      unsigned short h = bf_rne(f[8 + j]);
      float fh = __uint_as_float(((unsigned)h) << 16);
      hv1[j] = h;
      lv1[j] = bf_rne(f[8 + j] - fh);
    }
    *(ushort8*)(ah_w)     = hv0;
    *(ushort8*)(ah_w + 8) = hv1;
    *(ushort8*)(al_w)     = lv0;
    *(ushort8*)(al_w + 8) = lv1;

    __syncthreads();

#pragma unroll
    for (int ks = 0; ks < 2; ++ks) {
      const int ko = ks * 16;
      bf16x8 fa_h[2], fa_l[2], fb_h[2], fb_l[2];
#pragma unroll
      for (int ff = 0; ff < 2; ++ff) {
        fa_h[ff] = *(const bf16x8*)(a_rd[ff] + ko);
        fa_l[ff] = *(const bf16x8*)(a_rd[ff] + ko + lo_off_a);
        fb_h[ff] = *(const bf16x8*)(b_rd[ff] + ko);
        fb_l[ff] = *(const bf16x8*)(b_rd[ff] + ko + lo_off_b);
      }
#pragma unroll
      for (int i = 0; i < 2; ++i)
#pragma unroll
        for (int j = 0; j < 2; ++j) {
          acc[i][j] = __builtin_amdgcn_mfma_f32_32x32x16_bf16(fa_h[i], fb_h[j], acc[i][j], 0, 0, 0);
          acc[i][j] = __builtin_amdgcn_mfma_f32_32x32x16_bf16(fa_l[i], fb_h[j], acc[i][j], 0, 0, 0);
          acc[i][j] = __builtin_amdgcn_mfma_f32_32x32x16_bf16(fa_h[i], fb_l[j], acc[i][j], 0, 0, 0);
        }
    }
    __syncthreads();
  }

  // Epilogue: bias + relu. 32x32 C/D layout.
#pragma unroll
  for (int fn = 0; fn < 2; ++fn) {
    const int n = n0 + wn * 64 + fn * 32 + (lane & 31);
    const float bias = b1[n];
#pragma unroll
    for (int fm = 0; fm < 2; ++fm) {
      const int mbase = m0 + wm * 64 + fm * 32 + 4 * (lane >> 5);
#pragma unroll
      for (int reg = 0; reg < 16; ++reg) {
        const int row = mbase + (reg & 3) + 8 * (reg >> 2);
        float vv = acc[fm][fn][reg] + bias;
        Hout[(size_t)row * H_DIM + n] = fmaxf(vv, 0.f);
      }
    }
  }
}

// ---------------------------------------------------------------------------
// K2 fused: logits = h @ W2^T + b2 (bf16x3 MFMA) -> top-2 + weights + entropy.
// R4: BK=64 (half the barriers) + register prefetch of the h tile so the
// ~900cy HBM load overlaps the MFMA/LDS phase instead of serializing.
// ---------------------------------------------------------------------------
#define F_BM 64
#define F_BK 64

__global__ __launch_bounds__(256) void gemm2_router_kernel(
    const float* __restrict__ h,
    const unsigned short* __restrict__ w2h,
    const unsigned short* __restrict__ w2l,
    const float* __restrict__ b2,
    float* __restrict__ out, float* __restrict__ accum) {
  __shared__ unsigned short Ah[F_BM * F_BK];   // 8 KB each
  __shared__ unsigned short Al[F_BM * F_BK];
  __shared__ unsigned short Bh[E_DIM * F_BK];
  __shared__ unsigned short Bl[E_DIM * F_BK];
  __shared__ float LG[F_BM][E_DIM + 1];

  const int t    = threadIdx.x;
  const int lane = t & 63;
  const int w    = t >> 6;
  const int m0   = blockIdx.x * F_BM;

  // A staging: 16 contiguous fp32 along k per thread
  const int ar = t >> 2;           // row 0..63
  const int ac = (t & 3) * 16;     // col 0,16,32,48
  const float* hp = h + (size_t)(m0 + ar) * H_DIM + ac;
  unsigned short* ah_w = &Ah[ar * F_BK + ac];
  unsigned short* al_w = &Al[ar * F_BK + ac];

  // B staging: 2 async insts per plane per wave (wave base + lane*16B)
  const int e0 = (w * 2 + 0) * 512 + lane * 8;
  const int e1 = (w * 2 + 1) * 512 + lane * 8;
  const int r0 = e0 >> 6, c0 = e0 & 63;
  const int r1 = e1 >> 6, c1 = e1 & 63;
  const unsigned short* bh_g0 = w2h + (size_t)r0 * H_DIM + c0;
  const unsigned short* bh_g1 = w2h + (size_t)r1 * H_DIM + c1;
  const unsigned short* bl_g0 = w2l + (size_t)r0 * H_DIM + c0;
  const unsigned short* bl_g1 = w2l + (size_t)r1 * H_DIM + c1;
  unsigned short* bh_l0 = &Bh[e0];
  unsigned short* bh_l1 = &Bh[e1];
  unsigned short* bl_l0 = &Bl[e0];
  unsigned short* bl_l1 = &Bl[e1];

  // Fragment read addresses (16x16x32 frags; wave w owns rows w*16..+16)
  const int koff = (lane >> 4) * 8;
  const unsigned short* a_rd = &Ah[(w * 16 + (lane & 15)) * F_BK + koff];
  const unsigned short* b_rd[4];
#pragma unroll
  for (int f = 0; f < 4; ++f)
    b_rd[f] = &Bh[(f * 16 + (lane & 15)) * F_BK + koff];
  const int lo_off_a = (int)(Al - Ah);
  const int lo_off_b = (int)(Bl - Bh);

  f32x4 acc[4];
#pragma unroll
  for (int f = 0; f < 4; ++f) acc[f] = (f32x4)0.f;

  // prefetch iteration 0
  float4 p0 = *(const float4*)(hp);
  float4 p1 = *(const float4*)(hp + 4);
  float4 p2 = *(const float4*)(hp + 8);
  float4 p3 = *(const float4*)(hp + 12);

  for (int k0 = 0; k0 < H_DIM; k0 += F_BK) {
    // split prefetched A regs, stage to LDS
    float f[16] = {p0.x, p0.y, p0.z, p0.w, p1.x, p1.y, p1.z, p1.w,
                   p2.x, p2.y, p2.z, p2.w, p3.x, p3.y, p3.z, p3.w};
    ushort8 hv0, hv1, lv0, lv1;
#pragma unroll
    for (int j = 0; j < 8; ++j) {
      unsigned short hh = bf_rne(f[j]);
      float fh = __uint_as_float(((unsigned)hh) << 16);
      hv0[j] = hh;
      lv0[j] = bf_rne(f[j] - fh);
    }
#pragma unroll
    for (int j = 0; j < 8; ++j) {
      unsigned short hh = bf_rne(f[8 + j]);
      float fh = __uint_as_float(((unsigned)hh) << 16);
      hv1[j] = hh;
      lv1[j] = bf_rne(f[8 + j] - fh);
    }
    *(ushort8*)(ah_w)     = hv0;
    *(ushort8*)(ah_w + 8) = hv1;
    *(ushort8*)(al_w)     = lv0;
    *(ushort8*)(al_w + 8) = lv1;

    // async B for this chunk (W2 is L2-resident: short drain)
    async_copy16(bh_g0 + k0, bh_l0);
    async_copy16(bh_g1 + k0, bh_l1);
    async_copy16(bl_g0 + k0, bl_l0);
    async_copy16(bl_g1 + k0, bl_l1);

    __syncthreads();

    // prefetch next chunk's A (overlaps with MFMA below)
    if (k0 + F_BK < H_DIM) {
      const float* hpn = hp + k0 + F_BK;
      p0 = *(const float4*)(hpn);
      p1 = *(const float4*)(hpn + 4);
      p2 = *(const float4*)(hpn + 8);
      p3 = *(const float4*)(hpn + 12);
    }

#pragma unroll
    for (int ks = 0; ks < 2; ++ks) {
      const int ko = ks * 32;
      bf16x8 fa_h = *(const bf16x8*)(a_rd + ko);
      bf16x8 fa_l = *(const bf16x8*)(a_rd + ko + lo_off_a);
#pragma unroll
      for (int f = 0; f < 4; ++f) {
        bf16x8 fb_h = *(const bf16x8*)(b_rd[f] + ko);
        bf16x8 fb_l = *(const bf16x8*)(b_rd[f] + ko + lo_off_b);
        acc[f] = __builtin_amdgcn_mfma_f32_16x16x32_bf16(fa_h, fb_h, acc[f], 0, 0, 0);
        acc[f] = __builtin_amdgcn_mfma_f32_16x16x32_bf16(fa_l, fb_h, acc[f], 0, 0, 0);
        acc[f] = __builtin_amdgcn_mfma_f32_16x16x32_bf16(fa_h, fb_l, acc[f], 0, 0, 0);
      }
    }
    __syncthreads();
  }

  // Epilogue: bias, stash logits tile in LDS (16x16 C layout)
#pragma unroll
  for (int f = 0; f < 4; ++f) {
    const int e = f * 16 + (lane & 15);
    const float bias = b2[e];
#pragma unroll
    for (int r = 0; r < 4; ++r) {
      const int ml = w * 16 + (lane >> 4) * 4 + r;
      LG[ml][e] = acc[f][r] + bias;
    }
  }
  __syncthreads();

  // Router: threads 0..63 each own one row.
  if (t < F_BM) {
    const int row = m0 + t;
    float l0 = LG[t][0]; int i0 = 0;
    float l1 = -INFINITY; int i1 = -1;
#pragma unroll
    for (int e = 1; e < E_DIM; ++e) {
      float v = LG[t][e];
      if (v > l0)      { l1 = l0; i1 = i0; l0 = v; i0 = e; }
      else if (v > l1) { l1 = v; i1 = e; }
    }

    const float eT = expf((l1 - l0) / TEMP);
    const float w0 = 1.f / (1.f + eT);
    const float w1 = eT / (1.f + eT);

    float Z = 0.f;
#pragma unroll
    for (int e = 0; e < E_DIM; ++e) Z += expf(LG[t][e] - l0);
    const float invZ = 1.f / Z;
    float ent = 0.f;
#pragma unroll
    for (int e = 0; e < E_DIM; ++e) {
      float p = expf(LG[t][e] - l0) * invZ;
      ent -= p * logf(p + 1e-10f);
    }

    out[(size_t)row * 2 + 0] = w0;
    out[(size_t)row * 2 + 1] = w1;
    out[(size_t)B_ROWS * 2 + (size_t)row * 2 + 0] = (float)i0;
    out[(size_t)B_ROWS * 2 + (size_t)row * 2 + 1] = (float)i1;

#pragma unroll
    for (int off = 32; off > 0; off >>= 1) ent += __shfl_down(ent, off);
    if (t == 0) atomicAdd(accum, ent);
  }
}

__global__ void finalize_kernel(const float* __restrict__ accum,
                                float* __restrict__ out) {
  out[(size_t)B_ROWS * 4] = accum[0] / ((float)B_ROWS * logf((float)E_DIM));
}

// ---------------------------------------------------------------------------
extern "C" void kernel_launch(void* const* d_in, const int* in_sizes, int n_in,
                              void* d_out, int out_size, void* d_ws,
                              size_t ws_size, hipStream_t stream) {
  const float* x  = (const float*)d_in[0];
  const float* W1 = (const float*)d_in[1];
  const float* b1 = (const float*)d_in[2];
  const float* W2 = (const float*)d_in[3];
  const float* b2 = (const float*)d_in[4];
  float* out = (float*)d_out;

  unsigned short* w1h = (unsigned short*)d_ws;
  unsigned short* w1l = w1h + (size_t)H_DIM * D_DIM;
  unsigned short* w2h = w1l + (size_t)H_DIM * D_DIM;
  unsigned short* w2l = w2h + (size_t)E_DIM * H_DIM;
  float* h     = (float*)(w2l + (size_t)E_DIM * H_DIM);
  float* accum = h + (size_t)B_ROWS * H_DIM;

  split_kernel<<<(H_DIM * D_DIM) / (256 * 8), 256, 0, stream>>>(W1, w1h, w1l, nullptr);
  split_kernel<<<(E_DIM * H_DIM) / (256 * 8), 256, 0, stream>>>(W2, w2h, w2l, accum);

  dim3 g1(H_DIM / BN, B_ROWS / BM);  // (16, 128)
  gemm1_mfma_kernel<<<g1, 256, 0, stream>>>(x, w1h, w1l, b1, h);

  gemm2_router_kernel<<<B_ROWS / F_BM, 256, 0, stream>>>(h, w2h, w2l, b2, out, accum);

  finalize_kernel<<<1, 1, 0, stream>>>(accum, out);
}